// Round 1
// baseline (1853.804 us; speedup 1.0000x reference)
//
#include <hip/hip_runtime.h>
#include <math.h>

#define Dn 256
#define Hn 64

typedef __attribute__((ext_vector_type(8))) short short8;
typedef float floatx4 __attribute__((ext_vector_type(4)));

static __device__ __forceinline__ unsigned short f2bf(float x) {
    unsigned int u = __float_as_uint(x);
    unsigned int r = (u + 0x7fffu + ((u >> 16) & 1u)) >> 16;   // RNE
    return (unsigned short)r;
}

// ---------------------------------------------------------------------------
// prep_sgm: sgm[i*Dn + j] = sigmoid(adj[j*Dn + i]) * (j != i)
// grid 256 (i), block 256 (j)
// ---------------------------------------------------------------------------
__global__ __launch_bounds__(256) void prep_sgm(const float* __restrict__ adj,
                                                float* __restrict__ sgm) {
    const int i = blockIdx.x, j = threadIdx.x;
    float m = 0.f;
    if (j != i) m = 1.f / (1.f + __expf(-adj[(size_t)j * Dn + i]));
    sgm[(size_t)i * Dn + j] = m;
}

// ---------------------------------------------------------------------------
// prep_wb: masked bf16 weights in MFMA fragment layout (validated in R2).
// Fragment (i, c, nb, lane, e) <-> kk = nb*16 + (lane&15), j = c*32 + (lane>>4)*8 + e
// Wb offset (ushort): (((i*8 + c)*4 + nb)*64 + lane)*8 + e
// Layout serves as EITHER operand (A own-index = lane&15 = hidden when used as
// A-fragment; this is exploited by the operand-swapped MFMA in scm_main).
// grid (8, 256) = (c, i), block 256
// ---------------------------------------------------------------------------
__global__ __launch_bounds__(256) void prep_wb(const float* __restrict__ W1,
                                               const float* __restrict__ sgm,
                                               unsigned short* __restrict__ Wb) {
    const int c = blockIdx.x, i = blockIdx.y;
    const int t = threadIdx.x;
    const int nb = t >> 6, l = t & 63;
    const int kk = nb * 16 + (l & 15);
    const int jb = c * 32 + ((l >> 4) & 3) * 8;
    const float* wp = W1 + ((size_t)i * Hn + kk) * Dn + jb;
    const float* sp = sgm + (size_t)i * Dn + jb;
    unsigned short v[8];
#pragma unroll
    for (int e = 0; e < 8; ++e) v[e] = f2bf(wp[e] * sp[e]);
    unsigned short* dst = Wb + ((((size_t)i * 8 + c) * 4 + nb) * 64 + l) * 8;
    *(short8*)dst = *(const short8*)v;
}

// ---------------------------------------------------------------------------
// prep_nst: nsT[d*B + b] = exp(log_sigma[d]) * noise[b*Dn + d]  (64x64 tiles)
// grid (B/64, Dn/64), block 256
// ---------------------------------------------------------------------------
__global__ __launch_bounds__(256) void prep_nst(const float* __restrict__ noise,
                                                const float* __restrict__ ls,
                                                float* __restrict__ nsT, int B) {
    __shared__ float tile[64][65];
    const int bi = blockIdx.x * 64, dj = blockIdx.y * 64;
    const int t = threadIdx.x, c = t & 63, rq = t >> 6;
#pragma unroll
    for (int it = 0; it < 16; ++it) {
        int b = bi + it * 4 + rq;
        tile[it * 4 + rq][c] = noise[(size_t)b * Dn + dj + c];
    }
    __syncthreads();
#pragma unroll
    for (int it = 0; it < 16; ++it) {
        int d = dj + it * 4 + rq;
        float sg = __expf(ls[d]);
        nsT[(size_t)d * B + bi + c] = tile[c][it * 4 + rq] * sg;
    }
}

// ---------------------------------------------------------------------------
// scm_main (v2): operand-swapped MFMA + hidden-split across 4 waves.
//   block = 256 threads = 4 waves, ALL waves share ONE batch group of 16 rows
//   (rowbase = blockIdx.x*16). Wave w owns hidden tile w (units w*16..w*16+15).
//   Per step i (sec = i>>5):
//     D[hidden, batch] = sum_c mfma(Wfrag[i][c][w], Zfrag[c], .)   (A = weights!)
//     -> D layout: col(lane&15) = batch, row(q*4+r) = hidden-in-tile.
//   Per-lane epilogue: s = sum_r silu(D[r]+b1)*W2  (4 hiddens, NO shuffles).
//   Cross-lane+cross-wave reduce via tiny LDS pred buffer + 1 barrier/step
//   (parity double-buffered; raw lgkmcnt+s_barrier so weight prefetch vmcnt
//   stays in flight). Every lane then holds z of its own batch row n=lane&15,
//   so the in-progress z fragment 'ain' is updated IN-REGISTER (1 cndmask,
//   static element via 8-step sub-unroll). No z-history LDS at all.
//   Weights for step i+1 ((sec+1) frags = <=32 VGPRs/wave) prefetched during
//   the epilogue — fits registers now that hidden is split 4 ways.
// grid: B/16, block 256
// ---------------------------------------------------------------------------
__global__ __launch_bounds__(256, 2) void scm_main(const unsigned short* __restrict__ Wb,
                                                   const float* __restrict__ b1,
                                                   const float* __restrict__ W2,
                                                   const float* __restrict__ b2,
                                                   const float* __restrict__ nsT,
                                                   float* __restrict__ out, int B) {
    __shared__ float pred[2][16][5][4];   // [parity][n][q(+pad)][wave]
    const int t = threadIdx.x;
    const int w = t >> 6;                 // wave id == hidden tile
    const int l = t & 63;
    const int n = l & 15;                 // batch col (this lane's row)
    const int q = l >> 4;                 // 0..3
    const int rowbase = blockIdx.x * 16;
    const int hoff = w * 16 + q * 4;      // first of this lane's 4 hidden units

    // per-lane base into Wb for tile nb=w: frag(i,c) at wb_l + i*16384 + c*2048
    const unsigned short* wb_l = Wb + ((size_t)w * 64 + l) * 8;

    short8 af[8];                 // frozen z chunks (set at section boundaries)
    short8 wf[8];                 // current-step weight frags, chunks 0..sec
    const short8 zero8 = {0, 0, 0, 0, 0, 0, 0, 0};
    short8 ain = zero8;           // in-progress z chunk (register-resident)
    floatx4 b1v, w2v;
    float nvv, b2v;
    float zz[8];

    // preload step 0
    wf[0] = *(const short8*)(wb_l);
    b1v = *(const floatx4*)(b1 + hoff);
    w2v = *(const floatx4*)(W2 + hoff);
    nvv = nsT[rowbase + n];
    b2v = b2[0];

#pragma unroll
    for (int sec = 0; sec < 8; ++sec) {
        if (sec > 0) {
            af[sec - 1] = ain;            // promote completed chunk (reg copy)
            ain = zero8;
            // weights of the new in-progress chunk for this section's first
            // step (ain==0 there, but garbage bf16 * 0 could be NaN)
            wf[sec] = *(const short8*)(wb_l + (size_t)(sec * 32) * 16384 + sec * 2048);
        }
#pragma unroll 1
        for (int ii8 = 0; ii8 < 4; ++ii8) {
#pragma unroll
            for (int e8 = 0; e8 < 8; ++e8) {
                const int i = sec * 32 + ii8 * 8 + e8;

                // ---- MFMAs: A = weights, B = z history (swapped operands) ----
                floatx4 aA = {0.f, 0.f, 0.f, 0.f};
                floatx4 aB = {0.f, 0.f, 0.f, 0.f};
#pragma unroll
                for (int c = 0; c < 8; ++c) {
                    if (c < sec) {
                        if (c & 1) aB = __builtin_amdgcn_mfma_f32_16x16x32_bf16(wf[c], af[c], aB, 0, 0, 0);
                        else       aA = __builtin_amdgcn_mfma_f32_16x16x32_bf16(wf[c], af[c], aA, 0, 0, 0);
                    }
                }
                aB = __builtin_amdgcn_mfma_f32_16x16x32_bf16(wf[sec], ain, aB, 0, 0, 0);

                // ---- stash step-i epilogue params before prefetch clobbers ----
                floatx4 b1c = b1v, w2c = w2v;
                float nvc = nvv, b2c = b2v;

                // ---- prefetch step i+1 (flies during epilogue + barrier) ----
                {
                    int ip = i + 1; if (ip > 255) ip = 255;
                    const unsigned short* wp = wb_l + (size_t)ip * 16384;
#pragma unroll
                    for (int c = 0; c < 8; ++c)
                        if (c <= sec) wf[c] = *(const short8*)(wp + c * 2048);
                    b1v = *(const floatx4*)(b1 + ip * Hn + hoff);
                    w2v = *(const floatx4*)(W2 + ip * Hn + hoff);
                    nvv = nsT[(size_t)ip * B + rowbase + n];
                    b2v = b2[ip];
                }

                // ---- epilogue: per-lane partial over its 4 hidden units ----
                float s = 0.f;
#pragma unroll
                for (int r = 0; r < 4; ++r) {
                    float h = (aA[r] + aB[r]) + b1c[r];
                    s += __fdividef(h, 1.f + __expf(-h)) * w2c[r];
                }
                const int par = i & 1;
                pred[par][n][q][w] = s;
                // lgkm drain + barrier WITHOUT vmcnt(0): weight prefetch stays
                // in flight across the barrier.
                asm volatile("s_waitcnt lgkmcnt(0)\n\ts_barrier" ::: "memory");

                const floatx4* p4 = (const floatx4*)&pred[par][n][0][0];
                floatx4 v0 = p4[0], v1 = p4[1], v2 = p4[2], v3 = p4[3];
                float z = ((v0[0] + v0[1]) + (v0[2] + v0[3]))
                        + ((v1[0] + v1[1]) + (v1[2] + v1[3]))
                        + ((v2[0] + v2[1]) + (v2[2] + v2[3]))
                        + ((v3[0] + v3[1]) + (v3[2] + v3[3]));
                z += b2c + nvc;

                // ---- in-register z-fragment update (no LDS round trip) ----
                // lane (n,q) owns k = q*8+e of the chunk; col (i&31) lands in
                // group q == ii8, element e8 (both static/hoisted here).
                unsigned short zb = f2bf(z);
                ain[e8] = (q == ii8) ? (short)zb : ain[e8];
                zz[e8] = z;
            }
            // coalesced out flush: 8 steps = 32B per row, wave 0 only
            if (w == 0 && q == 0) {
                float* op = out + (size_t)(rowbase + n) * Dn + sec * 32 + ii8 * 8;
                floatx4 o0 = {zz[0], zz[1], zz[2], zz[3]};
                floatx4 o1 = {zz[4], zz[5], zz[6], zz[7]};
                *(floatx4*)(op) = o0;
                *(floatx4*)(op + 4) = o1;
            }
        }
    }
}

// ---------------------------------------------------------------------------
extern "C" void kernel_launch(void* const* d_in, const int* in_sizes, int n_in,
                              void* d_out, int out_size, void* d_ws, size_t ws_size,
                              hipStream_t stream) {
    const float* noise      = (const float*)d_in[0];
    const float* adj_logits = (const float*)d_in[1];
    const float* W1         = (const float*)d_in[2];
    const float* b1         = (const float*)d_in[3];
    const float* W2         = (const float*)d_in[4];
    const float* b2         = (const float*)d_in[5];
    const float* log_sigma  = (const float*)d_in[6];
    float* out = (float*)d_out;

    const int B = in_sizes[0] / Dn;                       // 8192
    // ws layout (16.78 MB total):
    //   [0, 8.39M)      : Wb   (bf16 fragment weights)
    //   [8.39M, 16.78M) : nsT  (fp32 transposed scaled noise);
    //                     sgm (256 KB) transiently occupies its start.
    unsigned short* Wb  = (unsigned short*)d_ws;
    float*          nsT = (float*)((char*)d_ws + (size_t)Dn * Dn * Hn * 2);
    float*          sgm = nsT;   // consumed by prep_wb before prep_nst overwrites

    prep_sgm<<<dim3(Dn), 256, 0, stream>>>(adj_logits, sgm);
    prep_wb<<<dim3(8, Dn), 256, 0, stream>>>(W1, sgm, Wb);
    prep_nst<<<dim3(B / 64, Dn / 64), 256, 0, stream>>>(noise, log_sigma, nsT, B);
    scm_main<<<dim3(B / 16), 256, 0, stream>>>(Wb, b1, W2, b2, nsT, out, B);
}

// Round 2
// 538.550 us; speedup vs baseline: 3.4422x; 3.4422x over previous
//
#include <hip/hip_runtime.h>
#include <math.h>

#define Dn 256
#define Hn 64

typedef __attribute__((ext_vector_type(8))) short short8;
typedef float floatx4 __attribute__((ext_vector_type(4)));

static __device__ __forceinline__ unsigned short f2bf(float x) {
    unsigned int u = __float_as_uint(x);
    unsigned int r = (u + 0x7fffu + ((u >> 16) & 1u)) >> 16;   // RNE
    return (unsigned short)r;
}

// async 16B/lane global -> LDS (dest = uniform base + lane*16)
static __device__ __forceinline__ void gll16(const unsigned short* g, unsigned short* l) {
    __builtin_amdgcn_global_load_lds(
        (const __attribute__((address_space(1))) unsigned int*)g,
        (__attribute__((address_space(3))) unsigned int*)l, 16, 0, 0);
}

// ---------------------------------------------------------------------------
// prep_sgm: sgm[i*Dn + j] = sigmoid(adj[j*Dn + i]) * (j != i)
// grid 256 (i), block 256 (j)
// ---------------------------------------------------------------------------
__global__ __launch_bounds__(256) void prep_sgm(const float* __restrict__ adj,
                                                float* __restrict__ sgm) {
    const int i = blockIdx.x, j = threadIdx.x;
    float m = 0.f;
    if (j != i) m = 1.f / (1.f + __expf(-adj[(size_t)j * Dn + i]));
    sgm[(size_t)i * Dn + j] = m;
}

// ---------------------------------------------------------------------------
// prep_wb: masked bf16 weights in MFMA B-fragment layout (validated in R2).
// Fragment (i, c, nb, lane, e) <-> kk = nb*16 + (lane&15), j = c*32 + (lane>>4)*8 + e
// Wb offset (ushort): (((i*8 + c)*4 + nb)*64 + lane)*8 + e
// grid (8, 256) = (c, i), block 256
// ---------------------------------------------------------------------------
__global__ __launch_bounds__(256) void prep_wb(const float* __restrict__ W1,
                                               const float* __restrict__ sgm,
                                               unsigned short* __restrict__ Wb) {
    const int c = blockIdx.x, i = blockIdx.y;
    const int t = threadIdx.x;
    const int nb = t >> 6, l = t & 63;
    const int kk = nb * 16 + (l & 15);
    const int jb = c * 32 + ((l >> 4) & 3) * 8;
    const float* wp = W1 + ((size_t)i * Hn + kk) * Dn + jb;
    const float* sp = sgm + (size_t)i * Dn + jb;
    unsigned short v[8];
#pragma unroll
    for (int e = 0; e < 8; ++e) v[e] = f2bf(wp[e] * sp[e]);
    unsigned short* dst = Wb + ((((size_t)i * 8 + c) * 4 + nb) * 64 + l) * 8;
    *(short8*)dst = *(const short8*)v;
}

// ---------------------------------------------------------------------------
// prep_nst: nsT[d*B + b] = exp(log_sigma[d]) * noise[b*Dn + d]  (64x64 tiles)
// grid (B/64, Dn/64), block 256
// ---------------------------------------------------------------------------
__global__ __launch_bounds__(256) void prep_nst(const float* __restrict__ noise,
                                                const float* __restrict__ ls,
                                                float* __restrict__ nsT, int B) {
    __shared__ float tile[64][65];
    const int bi = blockIdx.x * 64, dj = blockIdx.y * 64;
    const int t = threadIdx.x, c = t & 63, rq = t >> 6;
#pragma unroll
    for (int it = 0; it < 16; ++it) {
        int b = bi + it * 4 + rq;
        tile[it * 4 + rq][c] = noise[(size_t)b * Dn + dj + c];
    }
    __syncthreads();
#pragma unroll
    for (int it = 0; it < 16; ++it) {
        int d = dj + it * 4 + rq;
        float sg = __expf(ls[d]);
        nsT[(size_t)d * B + bi + c] = tile[c][it * 4 + rq] * sg;
    }
}

// ---------------------------------------------------------------------------
// scm_main (v3): v1's barrier-free structure + LDS weight double-buffer.
//   block = 128 threads = 2 waves; wave w owns rows blockIdx.x*32 + w*16 .. +15
//   and ALL 64 hidden units (4 N-tiles). Per step i:
//     C[16 x 64] = z[16 x K] * Wb[i][K x 64], K = 32*(sec+1).
//   CHANGE vs v1: weight fragments no longer live in registers (v1's bf[8][4]
//   needed 128 VGPRs; VGPR_Count=120 proved the compiler sank the prefetch,
//   exposing L3 latency every step since Wb=8.4MB thrashes the 4MiB L2).
//   Now: wave-private LDS double buffer filled by global_load_lds (async,
//   zero VGPR cost). Step i: s_waitcnt vmcnt(0) (buf[p] landed; loads had a
//   FULL STEP in flight), issue step i+1's loads into buf[1-p], then MFMA
//   from ds_read_b128 of buf[p]. In-progress MFMA skipped at ii==0 (its z
//   chunk is all zero), so no section-top weight special case is needed.
//   NO __syncthreads anywhere (both LDS regions are wave-private).
// grid: B/32, block 128
// ---------------------------------------------------------------------------
__global__ __launch_bounds__(128, 1) void scm_main(const unsigned short* __restrict__ Wb,
                                                   const float* __restrict__ b1,
                                                   const float* __restrict__ W2,
                                                   const float* __restrict__ b2,
                                                   const float* __restrict__ nsT,
                                                   float* __restrict__ out, int B) {
    __shared__ unsigned short zbf[32][264];        // bf16 z history; wave-private halves
    __shared__ unsigned short wst[2][2][8][4][512]; // [parity][wave][chunk][nb][lane*8] = 128KB
    const int t = threadIdx.x;
    const int w = t >> 6, l = t & 63;
    const int n = l & 15, q = l >> 4;
    const int rowbase = blockIdx.x * 32 + w * 16;

    // zero this wave's z history (wave-private -> no barrier needed)
    for (int idx = l; idx < 16 * 132; idx += 64) {
        int r = idx / 132, cc = idx - r * 132;
        ((unsigned int*)zbf[w * 16 + r])[cc] = 0u;
    }

    const unsigned short* zrow_lds = &zbf[w * 16 + n][0];   // this lane's A-row

    short8 af[8];          // frozen A chunks (z history, registers)
    float b1v[4], w2v[4], b2v;
    float4 nv;

    // preload step-0 epilogue params (weights not needed at step 0: z == 0)
    {
#pragma unroll
        for (int nb = 0; nb < 4; ++nb) {
            b1v[nb] = b1[nb * 16 + n];
            w2v[nb] = W2[nb * 16 + n];
        }
        nv  = *(const float4*)(nsT + rowbase + q * 4);
        b2v = b2[0];
    }

#pragma unroll
    for (int sec = 0; sec < 8; ++sec) {
        if (sec > 0) {
            // promote just-completed chunk into the register A-cache
            af[sec - 1] = *(const short8*)(zrow_lds + (sec - 1) * 32 + q * 8);
        }
#pragma unroll 1
        for (int ii = 0; ii < 32; ++ii) {
            const int i = sec * 32 + ii;
            const int p = ii & 1;

            // buf[p]'s loads were issued one full step ago -> drain them now.
            asm volatile("s_waitcnt vmcnt(0)" ::: "memory");

            // save current-step epilogue params before prefetch overwrites them
            float b1c[4], w2c[4], nvr[4];
            float b2c = b2v;
#pragma unroll
            for (int nb = 0; nb < 4; ++nb) { b1c[nb] = b1v[nb]; w2c[nb] = w2v[nb]; }
            nvr[0] = nv.x; nvr[1] = nv.y; nvr[2] = nv.z; nvr[3] = nv.w;

            // ---- prefetch step i+1: weights -> LDS buf[1-p], scalars -> regs.
            // Issued BEFORE this step's compute: a full step of in-flight time.
            {
                int ip = i + 1; if (ip > 255) ip = 255;
                const unsigned short* wrow = Wb + (size_t)ip * 16384 + l * 8;
#pragma unroll
                for (int c = 0; c < 8; ++c)
                    if (c <= sec) {
#pragma unroll
                        for (int nb = 0; nb < 4; ++nb)
                            gll16(wrow + c * 2048 + nb * 512, &wst[1 - p][w][c][nb][0]);
                    }
#pragma unroll
                for (int nb = 0; nb < 4; ++nb) {
                    b1v[nb] = b1[ip * Hn + nb * 16 + n];
                    w2v[nb] = W2[ip * Hn + nb * 16 + n];
                }
                nv  = *(const float4*)(nsT + (size_t)ip * B + rowbase + q * 4);
                b2v = b2[ip];
            }

            // ---- MFMAs from LDS buf[p] ----
            floatx4 zero4 = {0.f, 0.f, 0.f, 0.f};
            floatx4 acc[4];
#pragma unroll
            for (int nb = 0; nb < 4; ++nb) acc[nb] = zero4;

            // frozen chunks (register A-cache, weights from LDS)
#pragma unroll
            for (int c = 0; c < 8; ++c)
                if (c < sec) {
#pragma unroll
                    for (int nb = 0; nb < 4; ++nb) {
                        short8 bfr = *(const short8*)&wst[p][w][c][nb][l * 8];
                        acc[nb] = __builtin_amdgcn_mfma_f32_16x16x32_bf16(af[c], bfr, acc[nb], 0, 0, 0);
                    }
                }
            // in-progress chunk; skip on section's first step (its z cols are
            // all zero, and skipping removes the need to have chunk-sec
            // weights staged at section entry).
            if (ii != 0) {
                short8 ain = *(const short8*)(zrow_lds + sec * 32 + q * 8);
#pragma unroll
                for (int nb = 0; nb < 4; ++nb) {
                    short8 bfr = *(const short8*)&wst[p][w][sec][nb][l * 8];
                    acc[nb] = __builtin_amdgcn_mfma_f32_16x16x32_bf16(ain, bfr, acc[nb], 0, 0, 0);
                }
            }

            // epilogue: h = acc + b1; silu; dot W2 over all 64 hidden
            float d[4];
#pragma unroll
            for (int r = 0; r < 4; ++r) {
                float s = 0.f;
#pragma unroll
                for (int nb = 0; nb < 4; ++nb) {
                    float h = acc[nb][r] + b1c[nb];
                    s += __fdividef(h, 1.f + __expf(-h)) * w2c[nb];
                }
                d[r] = s;
            }
            // reduce over the 16 n-lanes (within each 16-lane group)
#pragma unroll
            for (int m = 1; m <= 8; m <<= 1) {
#pragma unroll
                for (int r = 0; r < 4; ++r) d[r] += __shfl_xor(d[r], m);
            }
            // z for rows q*4+r (all lanes of group q agree)
            float z[4];
#pragma unroll
            for (int r = 0; r < 4; ++r) z[r] = d[r] + b2c + nvr[r];

            // broadcast: zrow = z of row (l&15)
            int srcl = ((l & 15) >> 2) << 4;
            float t0 = __shfl(z[0], srcl), t1 = __shfl(z[1], srcl);
            float t2 = __shfl(z[2], srcl), t3 = __shfl(z[3], srcl);
            float za = (l & 1) ? t1 : t0;
            float zb = (l & 1) ? t3 : t2;
            float zrow = (l & 2) ? zb : za;

            if (q == 0) {   // lanes 0..15 of the wave: row n
                zbf[w * 16 + n][i] = f2bf(zrow);
                out[(size_t)(rowbase + n) * Dn + i] = zrow;
            }
        }
    }
}

// ---------------------------------------------------------------------------
extern "C" void kernel_launch(void* const* d_in, const int* in_sizes, int n_in,
                              void* d_out, int out_size, void* d_ws, size_t ws_size,
                              hipStream_t stream) {
    const float* noise      = (const float*)d_in[0];
    const float* adj_logits = (const float*)d_in[1];
    const float* W1         = (const float*)d_in[2];
    const float* b1         = (const float*)d_in[3];
    const float* W2         = (const float*)d_in[4];
    const float* b2         = (const float*)d_in[5];
    const float* log_sigma  = (const float*)d_in[6];
    float* out = (float*)d_out;

    const int B = in_sizes[0] / Dn;                       // 8192
    // ws layout (16.78 MB total):
    //   [0, 8.39M)      : Wb   (bf16 fragment weights)
    //   [8.39M, 16.78M) : nsT  (fp32 transposed scaled noise);
    //                     sgm (256 KB) transiently occupies its start.
    unsigned short* Wb  = (unsigned short*)d_ws;
    float*          nsT = (float*)((char*)d_ws + (size_t)Dn * Dn * Hn * 2);
    float*          sgm = nsT;   // consumed by prep_wb before prep_nst overwrites

    prep_sgm<<<dim3(Dn), 256, 0, stream>>>(adj_logits, sgm);
    prep_wb<<<dim3(8, Dn), 256, 0, stream>>>(W1, sgm, Wb);
    prep_nst<<<dim3(B / 64, Dn / 64), 256, 0, stream>>>(noise, log_sigma, nsT, B);
    scm_main<<<dim3(B / 32), 128, 0, stream>>>(Wb, b1, W2, b2, nsT, out, B);
}

// Round 3
// 402.226 us; speedup vs baseline: 4.6089x; 1.3389x over previous
//
#include <hip/hip_runtime.h>
#include <math.h>

#define Dn 256
#define Hn 64

typedef __attribute__((ext_vector_type(8))) short short8;
typedef __attribute__((ext_vector_type(4))) float floatx4;
typedef __attribute__((ext_vector_type(4))) unsigned int uint4v;

// anti-sink pin: force value to be materialized in a register HERE.
#define PIN(x) asm volatile("" :: "v"(x))

static __device__ __forceinline__ unsigned short f2bf(float x) {
    unsigned int u = __float_as_uint(x);
    unsigned int r = (u + 0x7fffu + ((u >> 16) & 1u)) >> 16;   // RNE
    return (unsigned short)r;
}

// ---------------------------------------------------------------------------
// prep_sgm: sgm[i*Dn + j] = sigmoid(adj[j*Dn + i]) * (j != i)
// grid 256 (i), block 256 (j)
// ---------------------------------------------------------------------------
__global__ __launch_bounds__(256) void prep_sgm(const float* __restrict__ adj,
                                                float* __restrict__ sgm) {
    const int i = blockIdx.x, j = threadIdx.x;
    float m = 0.f;
    if (j != i) m = 1.f / (1.f + __expf(-adj[(size_t)j * Dn + i]));
    sgm[(size_t)i * Dn + j] = m;
}

// ---------------------------------------------------------------------------
// prep_wb: masked bf16 weights in MFMA fragment layout (validated R2/v2).
// Fragment (i, c, nb, lane, e) <-> kk = nb*16 + (lane&15), j = c*32 + (lane>>4)*8 + e
// Wb offset (ushort): (((i*8 + c)*4 + nb)*64 + lane)*8 + e
// Used as the A-operand of mfma(W, Z): M-index = lane&15 = hidden,
// k = (lane>>4)*8 + e  (validated end-to-end by the passing v2 run).
// grid (8, 256) = (c, i), block 256
// ---------------------------------------------------------------------------
__global__ __launch_bounds__(256) void prep_wb(const float* __restrict__ W1,
                                               const float* __restrict__ sgm,
                                               unsigned short* __restrict__ Wb) {
    const int c = blockIdx.x, i = blockIdx.y;
    const int t = threadIdx.x;
    const int nb = t >> 6, l = t & 63;
    const int kk = nb * 16 + (l & 15);
    const int jb = c * 32 + ((l >> 4) & 3) * 8;
    const float* wp = W1 + ((size_t)i * Hn + kk) * Dn + jb;
    const float* sp = sgm + (size_t)i * Dn + jb;
    unsigned short v[8];
#pragma unroll
    for (int e = 0; e < 8; ++e) v[e] = f2bf(wp[e] * sp[e]);
    unsigned short* dst = Wb + ((((size_t)i * 8 + c) * 4 + nb) * 64 + l) * 8;
    *(short8*)dst = *(const short8*)v;
}

// ---------------------------------------------------------------------------
// prep_nst: nsT[d*B + b] = exp(log_sigma[d]) * noise[b*Dn + d]  (64x64 tiles)
// grid (B/64, Dn/64), block 256
// ---------------------------------------------------------------------------
__global__ __launch_bounds__(256) void prep_nst(const float* __restrict__ noise,
                                                const float* __restrict__ ls,
                                                float* __restrict__ nsT, int B) {
    __shared__ float tile[64][65];
    const int bi = blockIdx.x * 64, dj = blockIdx.y * 64;
    const int t = threadIdx.x, c = t & 63, rq = t >> 6;
#pragma unroll
    for (int it = 0; it < 16; ++it) {
        int b = bi + it * 4 + rq;
        tile[it * 4 + rq][c] = noise[(size_t)b * Dn + dj + c];
    }
    __syncthreads();
#pragma unroll
    for (int it = 0; it < 16; ++it) {
        int d = dj + it * 4 + rq;
        float sg = __expf(ls[d]);
        nsT[(size_t)d * B + bi + c] = tile[c][it * 4 + rq] * sg;
    }
}

// ---------------------------------------------------------------------------
// scm_main (v4): v1's barrier-free per-wave independence + v2's validated
// swapped-operand math + anti-sink register prefetch. ZERO LDS.
//   block = 128 = 2 independent waves; wave w owns 16 batch rows
//   (rowbase = blockIdx.x*32 + w*16) and ALL 64 hidden units.
//   Lane (n = l&15, q = l>>4):
//     z B-frags: lane holds z[k = q*8+e][row n]  -> ain/af in REGISTERS,
//       updated by masked bit-insert (static word index, dynamic shift).
//     W A-frags: wf[c][nb] (Wb layout reused as A; proven by v2).
//     D[hidden = q*4+r (tile nb)][batch = n] -> epilogue fully per-lane:
//       s = sum_{nb,r} silu(acc + b1)*W2, then TWO shfl_xor rounds (16, 32);
//       every lane ends with z of its own row -> no broadcast, no z-LDS.
//   Weight prefetch: distance-1 into single-buffered wf regs (128 VGPR,
//   free at 0.5 waves/SIMD), issued right after the MFMA section; PINned
//   (asm volatile "v") at the END of the body so the compiler cannot sink
//   the loads into the next step (v1's proven failure, VGPR=120). The
//   waitcnt lands after the ~500-cyc epilogue -> L3 latency hidden.
// grid: B/32, block 128
// ---------------------------------------------------------------------------
__global__ __launch_bounds__(128, 1) void scm_main(const unsigned short* __restrict__ Wb,
                                                   const float* __restrict__ b1,
                                                   const float* __restrict__ W2,
                                                   const float* __restrict__ b2,
                                                   const float* __restrict__ nsT,
                                                   float* __restrict__ out, int B) {
    const int t = threadIdx.x;
    const int w = t >> 6, l = t & 63;
    const int n = l & 15, q = l >> 4;
    const int rowbase = blockIdx.x * 32 + w * 16;

    const unsigned short* wb_l = Wb + (size_t)l * 8;

    short8 af[8];                    // frozen z chunks (registers)
    short8 wf[8][4];                 // current-step weight A-frags
    uint4v ain = {0u, 0u, 0u, 0u};   // in-progress z chunk (registers)
    floatx4 b1v[4], w2v[4];
    float nvv, b2v;

    // preload step-0 epilogue params (step 0 issues no MFMAs: z == 0)
#pragma unroll
    for (int nb = 0; nb < 4; ++nb) {
        b1v[nb] = *(const floatx4*)(b1 + nb * 16 + q * 4);
        w2v[nb] = *(const floatx4*)(W2 + nb * 16 + q * 4);
    }
    nvv = nsT[rowbase + n];
    b2v = b2[0];

#pragma unroll
    for (int sec = 0; sec < 8; ++sec) {
        if (sec > 0) {
            af[sec - 1] = __builtin_bit_cast(short8, ain);   // register copy
            ain = (uint4v){0u, 0u, 0u, 0u};
        }
#pragma unroll 1
        for (int ii = 0; ii < 32; ++ii) {
            const int i = sec * 32 + ii;

            floatx4 aA[4], aB[4];
#pragma unroll
            for (int nb = 0; nb < 4; ++nb) {
                aA[nb] = (floatx4){0.f, 0.f, 0.f, 0.f};
                aB[nb] = (floatx4){0.f, 0.f, 0.f, 0.f};
            }

            // in-progress chunk FIRST (depends on ain from previous step);
            // skipped on a section's first step (its z cols are all zero).
            if (ii != 0) {
                short8 zi = __builtin_bit_cast(short8, ain);
#pragma unroll
                for (int nb = 0; nb < 4; ++nb)
                    aB[nb] = __builtin_amdgcn_mfma_f32_16x16x32_bf16(wf[sec][nb], zi, aB[nb], 0, 0, 0);
            }
            // frozen chunks (independent of z_{i-1}; fill the pipe)
#pragma unroll
            for (int c = 0; c < 8; ++c)
                if (c < sec) {
#pragma unroll
                    for (int nb = 0; nb < 4; ++nb)
                        aA[nb] = __builtin_amdgcn_mfma_f32_16x16x32_bf16(wf[c][nb], af[c], aA[nb], 0, 0, 0);
                }

            // stash current-step epilogue params before prefetch overwrites
            floatx4 b1c[4], w2c[4];
            float nvc = nvv, b2c = b2v;
#pragma unroll
            for (int nb = 0; nb < 4; ++nb) { b1c[nb] = b1v[nb]; w2c[nb] = w2v[nb]; }

            // prefetch step i+1 (issued early; in flight across the epilogue)
            {
                int ip = i + 1; if (ip > 255) ip = 255;
                const unsigned short* wp = wb_l + (size_t)ip * 16384;
#pragma unroll
                for (int c = 0; c < 8; ++c)
                    if (c <= sec) {
#pragma unroll
                        for (int nb = 0; nb < 4; ++nb)
                            wf[c][nb] = *(const short8*)(wp + c * 2048 + nb * 512);
                    }
#pragma unroll
                for (int nb = 0; nb < 4; ++nb) {
                    b1v[nb] = *(const floatx4*)(b1 + ip * Hn + nb * 16 + q * 4);
                    w2v[nb] = *(const floatx4*)(W2 + ip * Hn + nb * 16 + q * 4);
                }
                nvv = nsT[(size_t)ip * B + rowbase + n];
                b2v = b2[ip];
            }

            // epilogue: fully per-lane hidden dot (16 units: 4 nb x 4 r)
            float s = 0.f;
#pragma unroll
            for (int nb = 0; nb < 4; ++nb) {
#pragma unroll
                for (int r = 0; r < 4; ++r) {
                    float h = (aA[nb][r] + aB[nb][r]) + b1c[nb][r];
                    s += __fdividef(h, 1.f + __expf(-h)) * w2c[nb][r];
                }
            }
            // reduce over the 4 q-groups: 2 rounds, no broadcast needed
            s += __shfl_xor(s, 16);
            s += __shfl_xor(s, 32);
            float z = s + b2c + nvc;

            // in-register z insert: lane (n,q) owns k=ii iff q == ii>>3;
            // element e = ii&7 -> word (ii>>1)&3 (static), half ii&1 (shift).
            {
                unsigned int zb = (unsigned int)f2bf(z);
                unsigned int sh = (unsigned int)(ii & 1) << 4;
                unsigned int val = zb << sh;
                unsigned int msk = 0xFFFFu << sh;
                const int own = (q == (ii >> 3));
                const int wsel = (ii >> 1) & 3;
#pragma unroll
                for (int wd = 0; wd < 4; ++wd) {
                    unsigned int merged = (ain[wd] & ~msk) | val;
                    ain[wd] = (own && (wsel == wd)) ? merged : ain[wd];
                }
            }

            if (q == 0) out[(size_t)(rowbase + n) * Dn + i] = z;

            // anti-sink pins: prefetched values must be in registers HERE.
#pragma unroll
            for (int c = 0; c < 8; ++c)
                if (c <= sec) {
#pragma unroll
                    for (int nb = 0; nb < 4; ++nb) PIN(wf[c][nb]);
                }
#pragma unroll
            for (int nb = 0; nb < 4; ++nb) { PIN(b1v[nb]); PIN(w2v[nb]); }
            PIN(nvv); PIN(b2v);
        }
    }
}

// ---------------------------------------------------------------------------
extern "C" void kernel_launch(void* const* d_in, const int* in_sizes, int n_in,
                              void* d_out, int out_size, void* d_ws, size_t ws_size,
                              hipStream_t stream) {
    const float* noise      = (const float*)d_in[0];
    const float* adj_logits = (const float*)d_in[1];
    const float* W1         = (const float*)d_in[2];
    const float* b1         = (const float*)d_in[3];
    const float* W2         = (const float*)d_in[4];
    const float* b2         = (const float*)d_in[5];
    const float* log_sigma  = (const float*)d_in[6];
    float* out = (float*)d_out;

    const int B = in_sizes[0] / Dn;                       // 8192
    // ws layout (16.78 MB total):
    //   [0, 8.39M)      : Wb   (bf16 fragment weights)
    //   [8.39M, 16.78M) : nsT  (fp32 transposed scaled noise);
    //                     sgm (256 KB) transiently occupies its start.
    unsigned short* Wb  = (unsigned short*)d_ws;
    float*          nsT = (float*)((char*)d_ws + (size_t)Dn * Dn * Hn * 2);
    float*          sgm = nsT;   // consumed by prep_wb before prep_nst overwrites

    prep_sgm<<<dim3(Dn), 256, 0, stream>>>(adj_logits, sgm);
    prep_wb<<<dim3(8, Dn), 256, 0, stream>>>(W1, sgm, Wb);
    prep_nst<<<dim3(B / 64, Dn / 64), 256, 0, stream>>>(noise, log_sigma, nsT, B);
    scm_main<<<dim3(B / 32), 128, 0, stream>>>(Wb, b1, W2, b2, nsT, out, B);
}